// Round 2
// 270.811 us; speedup vs baseline: 1.1310x; 1.1310x over previous
//
#include <hip/hip_runtime.h>
#include <hip/hip_bf16.h>

typedef __attribute__((ext_vector_type(8))) short short8;
typedef __attribute__((ext_vector_type(4))) float floatx4;
typedef __attribute__((ext_vector_type(4))) unsigned short ushortx4;

#define TT 4
#define XS_PITCH 136   // 4*32 + 8 pad: 272B rows, breaks pow2 bank stride, keeps 16B align

// workspace layout (bytes)
#define WS_W2 0        // bf16 [64][192]   : W2[co][k*64+c] = Wc[k*64+co][c]
#define WS_AE 24576    // bf16 [3][32][32] : ae[k][w][v] = Aeff[k][v][w], zero-padded
#define WS_F  30720    // f32  [32][64]    : F[w][co] = s*bterm + beta - mean*s (rows>=25 = 0)
#define WS_S  38912    // f32  [64]        : s[co] = gamma*rsqrt(var+eps)

__device__ __forceinline__ float bf2f(unsigned short u) {
    return __uint_as_float(((unsigned int)u) << 16);
}
__device__ __forceinline__ unsigned short f2bf(float f) {
    unsigned int xx = __float_as_uint(f);
    return (unsigned short)((xx + 0x7fffu + ((xx >> 16) & 1u)) >> 16);
}

// ---------------- prep: fold all constants once (runs in ~2 us) ----------------
__global__ __launch_bounds__(256) void gcn_prep(
    const float* __restrict__ A, const float* __restrict__ PA,
    const float* __restrict__ Wc, const float* __restrict__ bc,
    const float* __restrict__ gamma_, const float* __restrict__ beta_,
    const float* __restrict__ mean_, const float* __restrict__ var_,
    unsigned short* __restrict__ w2, unsigned short* __restrict__ ae,
    float* __restrict__ Fx, float* __restrict__ sarr)
{
    const int b = blockIdx.x, tid = threadIdx.x;
    if (b == 0) {
        __shared__ float cs[96];
        if (tid < 96) {
            int k = tid >> 5, w = tid & 31;
            float s = 0.f;
            if (w < 25)
                for (int v = 0; v < 25; ++v) {
                    int ai = (k * 25 + v) * 25 + w;
                    s += A[ai] * PA[ai];
                }
            cs[tid] = s;
        }
        if (tid < 64) sarr[tid] = gamma_[tid] * rsqrtf(var_[tid] + 1e-5f);
        __syncthreads();
        for (int e = tid; e < 2048; e += 256) {
            int w = e >> 6, co = e & 63;
            float val = 0.f;
            if (w < 25) {
                float sc = gamma_[co] * rsqrtf(var_[co] + 1e-5f);
                val = beta_[co] - mean_[co] * sc
                    + sc * (bc[co] * cs[w] + bc[64 + co] * cs[32 + w] + bc[128 + co] * cs[64 + w]);
            }
            Fx[e] = val;
        }
    } else if (b == 1) {
        for (int e = tid; e < 3072; e += 256) {
            int k = e >> 10, r = e & 1023, w = r >> 5, v = r & 31;
            unsigned short val = 0;
            if (v < 25 && w < 25) {
                int ai = (k * 25 + v) * 25 + w;
                val = f2bf(A[ai] * PA[ai]);
            }
            ae[e] = val;  // [k][w][v] holds Aeff[k][v][w]
        }
    } else {
        const int half = b - 2;
        for (int e = tid + half * 6144; e < (half + 1) * 6144; e += 256) {
            int co = e / 192, kc = e % 192, k = kc >> 6, c = kc & 63;
            w2[e] = f2bf(Wc[(k * 64 + co) * 64 + c]);
        }
    }
}

// ---------------- main: wave-private t, 1 barrier/block, no inter-wave LDS ----------------
// LDS: Xs 17408 + XAbuf 16384 = 33792 B -> 4 blocks/CU at VGPR<=128
__global__ __launch_bounds__(256, 4) void gcn_main(
    const float* __restrict__ x,
    const unsigned short* __restrict__ w2g,
    const unsigned short* __restrict__ aeg,
    const float* __restrict__ Fg,
    const float* __restrict__ sg,
    float* __restrict__ out)
{
#if defined(__gfx950__)
    __shared__ __align__(16) unsigned short Xs[64 * XS_PITCH];   // bf16 [c][t*32+v]
    __shared__ __align__(16) unsigned short XAbuf[4 * 2 * 1024]; // per-wave double buffer, 2KB each

    const int tid = threadIdx.x;
    const int n  = blockIdx.x >> 6;
    const int t0 = (blockIdx.x & 63) * TT;
    const float* xn = x + (size_t)n * 409600;

    // ---- stage x tile: one (c,t) row of 25 floats per thread, b128 LDS writes ----
    {
        const int c = tid >> 2, tl = tid & 3;
        const float* gp = xn + (c * 256 + t0 + tl) * 25;
        unsigned short* dst = &Xs[c * XS_PITCH + tl * 32];
        float f[32];
#pragma unroll
        for (int j = 0; j < 25; ++j) f[j] = gp[j];
#pragma unroll
        for (int j = 25; j < 32; ++j) f[j] = 0.f;
#pragma unroll
        for (int vc = 0; vc < 4; ++vc) {
            union { short8 v; unsigned short s[8]; } u;
#pragma unroll
            for (int j = 0; j < 8; ++j) u.s[j] = f2bf(f[vc * 8 + j]);
            *(short8*)&dst[vc * 8] = u.v;
        }
    }

    const int wave = tid >> 6, lane = tid & 63;
    const int l15 = lane & 15, quad = lane >> 4;
    const int t = wave;   // wave-private t

    // Aeff B-fragments from ws (L2-resident): lane holds Aeff[k][v=quad*8+j][w=nt*16+l15]
    short8 aeffB[3][2];
#pragma unroll
    for (int k = 0; k < 3; ++k)
#pragma unroll
        for (int nt = 0; nt < 2; ++nt)
            aeffB[k][nt] = *(const short8*)&aeg[(k * 32 + nt * 16 + l15) * 32 + quad * 8];

    __syncthreads();   // the only barrier in the kernel

    unsigned short* xa = &XAbuf[wave * 2048];
    // XAbuf row = w (64B = 4 x 16B chunks), col = c-in-chunk; chunk XOR-swizzled by (w&3)
    const int wlo3 = l15 & 3, qh = quad >> 1, ql = quad & 1;
    const int woff00 = (l15     ) * 64 + (((0 + qh) ^ wlo3) << 4) + ql * 8;  // mt0 nt0
    const int woff01 = (16 + l15) * 64 + (((0 + qh) ^ wlo3) << 4) + ql * 8;  // mt0 nt1
    const int woff10 = (l15     ) * 64 + (((2 + qh) ^ wlo3) << 4) + ql * 8;  // mt1 nt0
    const int woff11 = (16 + l15) * 64 + (((2 + qh) ^ wlo3) << 4) + ql * 8;  // mt1 nt1
    const int roff0  = (l15     ) * 64 + ((quad ^ wlo3) << 4);
    const int roff1  = (16 + l15) * 64 + ((quad ^ wlo3) << 4);

    const floatx4 zero4 = {0.f, 0.f, 0.f, 0.f};
    floatx4 zacc[4][2];
#pragma unroll
    for (int ct = 0; ct < 4; ++ct) { zacc[ct][0] = zero4; zacc[ct][1] = zero4; }

    const unsigned short* xsrow = &Xs[t * 32 + quad * 8];

#pragma unroll
    for (int ch = 0; ch < 6; ++ch) {
        const int k = ch >> 1, cc = ch & 1;
        char* xab = (char*)xa + (ch & 1) * 2048;

        // ---- stage A: XA[c',w] = sum_v X[c',v] * Aeff_k[v,w]  (c' = this 32-chunk) ----
        short8 xf0 = *(const short8*)&xsrow[(cc * 32      + l15) * XS_PITCH];
        short8 xf1 = *(const short8*)&xsrow[(cc * 32 + 16 + l15) * XS_PITCH];
        floatx4 d00 = __builtin_amdgcn_mfma_f32_16x16x32_bf16(xf0, aeffB[k][0], zero4, 0, 0, 0);
        floatx4 d01 = __builtin_amdgcn_mfma_f32_16x16x32_bf16(xf0, aeffB[k][1], zero4, 0, 0, 0);
        floatx4 d10 = __builtin_amdgcn_mfma_f32_16x16x32_bf16(xf1, aeffB[k][0], zero4, 0, 0, 0);
        floatx4 d11 = __builtin_amdgcn_mfma_f32_16x16x32_bf16(xf1, aeffB[k][1], zero4, 0, 0, 0);

        // D rows = 4 consecutive c' -> pack bf16x4, one b64 write each (swizzled)
        {
            ushortx4 p;
            p[0] = f2bf(d00[0]); p[1] = f2bf(d00[1]); p[2] = f2bf(d00[2]); p[3] = f2bf(d00[3]);
            *(ushortx4*)(xab + woff00) = p;
            p[0] = f2bf(d01[0]); p[1] = f2bf(d01[1]); p[2] = f2bf(d01[2]); p[3] = f2bf(d01[3]);
            *(ushortx4*)(xab + woff01) = p;
            p[0] = f2bf(d10[0]); p[1] = f2bf(d10[1]); p[2] = f2bf(d10[2]); p[3] = f2bf(d10[3]);
            *(ushortx4*)(xab + woff10) = p;
            p[0] = f2bf(d11[0]); p[1] = f2bf(d11[1]); p[2] = f2bf(d11[2]); p[3] = f2bf(d11[3]);
            *(ushortx4*)(xab + woff11) = p;
        }

        // ---- stage B: Z[co,w] += W2[co, kc-chunk] @ XA[kc-chunk, w] (same-wave RAW, no barrier) ----
        short8 b0 = *(const short8*)(xab + roff0);
        short8 b1 = *(const short8*)(xab + roff1);
        const unsigned short* wrow = &w2g[l15 * 192 + k * 64 + cc * 32 + quad * 8];
#pragma unroll
        for (int ct = 0; ct < 4; ++ct) {
            short8 wf = *(const short8*)&wrow[ct * 16 * 192];
            zacc[ct][0] = __builtin_amdgcn_mfma_f32_16x16x32_bf16(wf, b0, zacc[ct][0], 0, 0, 0);
            zacc[ct][1] = __builtin_amdgcn_mfma_f32_16x16x32_bf16(wf, b1, zacc[ct][1], 0, 0, 0);
        }
    }

    // ---- epilogue: val = s[co]*z + F[w][co] + residual, relu, store ----
    const unsigned short* resp = &Xs[(quad * 4) * XS_PITCH + t * 32 + l15];
    float* outp = out + ((size_t)(n * 64 + quad * 4) * 256 + t0 + t) * 25 + l15;
#pragma unroll
    for (int ct = 0; ct < 4; ++ct) {
        floatx4 sv = *(const floatx4*)&sg[ct * 16 + quad * 4];
#pragma unroll
        for (int wt = 0; wt < 2; ++wt) {
            floatx4 Fv = *(const floatx4*)&Fg[(wt * 16 + l15) * 64 + ct * 16 + quad * 4];
            if (wt == 0 || l15 < 9) {   // w = wt*16 + l15 < 25
#pragma unroll
                for (int r = 0; r < 4; ++r) {
                    float xres = bf2f(resp[(ct * 16 + r) * XS_PITCH + wt * 16]);
                    float val = sv[r] * zacc[ct][wt][r] + Fv[r] + xres;
                    outp[(size_t)(ct * 16 + r) * 6400 + wt * 16] = fmaxf(val, 0.f);
                }
            }
        }
    }
#else
    (void)x; (void)w2g; (void)aeg; (void)Fg; (void)sg; (void)out;
#endif
}

extern "C" void kernel_launch(void* const* d_in, const int* in_sizes, int n_in,
                              void* d_out, int out_size, void* d_ws, size_t ws_size,
                              hipStream_t stream) {
    (void)in_sizes; (void)n_in; (void)out_size; (void)ws_size;
    unsigned short* w2 = (unsigned short*)((char*)d_ws + WS_W2);
    unsigned short* ae = (unsigned short*)((char*)d_ws + WS_AE);
    float*          Fx = (float*)((char*)d_ws + WS_F);
    float*          sa = (float*)((char*)d_ws + WS_S);

    gcn_prep<<<dim3(4), dim3(256), 0, stream>>>(
        (const float*)d_in[1], (const float*)d_in[2], (const float*)d_in[3],
        (const float*)d_in[4], (const float*)d_in[5], (const float*)d_in[6],
        (const float*)d_in[7], (const float*)d_in[8], w2, ae, Fx, sa);

    gcn_main<<<dim3(64 * 64), dim3(256), 0, stream>>>(
        (const float*)d_in[0], w2, ae, Fx, sa, (float*)d_out);
}